// Round 11
// baseline (287.459 us; speedup 1.0000x reference)
//
#include <hip/hip_runtime.h>
#include <hip/hip_bf16.h>

#define N_NODES 50000
#define IN_CH 128
#define HID 128
#define OUT_CH 64
#define N_EDGES 800000
#define N_TOT_EDGES (N_EDGES + N_NODES)         // + self loops
#define ET_PAD (N_TOT_EDGES + 3 * N_NODES)      // worst-case pad-to-4 per node

typedef unsigned uint4v __attribute__((ext_vector_type(4)));
typedef float    float4v __attribute__((ext_vector_type(4)));

// ---------------- CSR build ----------------

__global__ void k_init(int* cnt, int* cur, float* alsA, float* aldA,
                       float* alsB, float* aldB, int n) {
    int i = blockIdx.x * 256 + threadIdx.x;
    if (i < n) {
        cnt[i] = 1; cur[i] = 0;              // self-loop contributes 1
        alsA[i] = 0.f; aldA[i] = 0.f;        // per-layer attention-dot accumulators
        alsB[i] = 0.f; aldB[i] = 0.f;        // (gemm atomically accumulates tile partials)
    }
}

__global__ void k_count(const int* __restrict__ dst_row, int* __restrict__ cnt, int e) {
    int i = blockIdx.x * 256 + threadIdx.x;
    if (i < e) atomicAdd(&cnt[dst_row[i]], 1);
}

// inclusive scan of PADDED counts -> off[i+1]; per-block sums to bsum.
// Segments padded to 4 so the SpMM can use aligned uint4 ew loads, no tail.
__global__ void k_scan1(const int* __restrict__ cnt, int* __restrict__ off,
                        int* __restrict__ bsum, int n) {
    __shared__ int s[256];
    int t = threadIdx.x;
    int i = blockIdx.x * 256 + t;
    int v = (i < n) ? ((cnt[i] + 3) & ~3) : 0;
    s[t] = v;
    __syncthreads();
    for (int d = 1; d < 256; d <<= 1) {
        int x = (t >= d) ? s[t - d] : 0;
        __syncthreads();
        s[t] += x;
        __syncthreads();
    }
    if (i < n) off[i + 1] = s[t];
    if (t == 255) bsum[blockIdx.x] = s[255];
}

__global__ void k_scan2(int* __restrict__ bsum, int nb) {  // single block, nb <= 256
    __shared__ int s[256];
    int t = threadIdx.x;
    int v = (t < nb) ? bsum[t] : 0;
    s[t] = v;
    __syncthreads();
    for (int d = 1; d < 256; d <<= 1) {
        int x = (t >= d) ? s[t - d] : 0;
        __syncthreads();
        s[t] += x;
        __syncthreads();
    }
    if (t < nb) bsum[t] = s[t] - v;  // exclusive prefix
}

__global__ void k_scan3(int* __restrict__ off, const int* __restrict__ bsum, int n) {
    int i = blockIdx.x * 256 + threadIdx.x;
    if (i < n) off[i + 1] += bsum[blockIdx.x];
    if (i == 0) off[0] = 0;
}

__global__ void k_fill(const int* __restrict__ ei, const int* __restrict__ off,
                       int* __restrict__ cur, int* __restrict__ csr, int e, int n) {
    int i = blockIdx.x * 256 + threadIdx.x;
    if (i >= e + n) return;
    int src, dst;
    if (i < e) { src = ei[i]; dst = ei[e + i]; }
    else       { src = dst = i - e; }
    int pos = off[dst] + atomicAdd(&cur[dst], 1);
    csr[pos] = src;
}

// ---------------- GEMM (h = X @ W) + fused attention dots ----------------
// Only W (the reused operand) staged in LDS: 64-col tile = 32KB -> 4-5 blocks/CU.
// X streams from global (broadcast float4 reads). 64x64 tile, thread = 4x4.
// H written CHUNK-MAJOR Hc[chunk][row][16] (3.2MB slice, XCD-L2-resident for
// the SpMM). Attention dots: shfl_xor over 16 col-lanes + one atomicAdd per
// (row, col-tile) into zero-initialized per-layer buffers (deterministic).
template<int N>
__global__ __launch_bounds__(256) void gemm_att(
        const float* __restrict__ X, const float* __restrict__ W,
        const float* __restrict__ asrc, const float* __restrict__ adst,
        float* __restrict__ Hc, float* __restrict__ als, float* __restrict__ ald,
        int M) {
    constexpr int K = 128;
    constexpr int CT = N / 64;                 // col tiles (2 or 1)
    __shared__ float Ws[K * 64];               // 32 KB
    const int ct = blockIdx.x % CT;
    const int r0 = (blockIdx.x / CT) * 64;
    const int t  = threadIdx.x;
    const int c  = t & 15;                     // col group (4 cols each)
    const int rg = t >> 4;                     // row group (4 rows each)
    const int col = ct * 64 + c * 4;

    // stage W col-tile: linear float4 copies, conflict-free
    for (int i = t * 4; i < K * 64; i += 1024) {
        int k = i >> 6, cc = i & 63;
        *(float4*)&Ws[i] = *(const float4*)&W[(size_t)k * N + ct * 64 + cc];
    }
    __syncthreads();

    // clamp OOB rows to M-1 (results discarded at write)
    const float* Xr[4];
    #pragma unroll
    for (int r = 0; r < 4; ++r) {
        int row = r0 + rg * 4 + r; if (row >= M) row = M - 1;
        Xr[r] = X + (size_t)row * K;
    }

    float acc[4][4] = {};
    for (int k0 = 0; k0 < K; k0 += 4) {
        float4 xv[4], wv[4];
        #pragma unroll
        for (int r = 0; r < 4; ++r) xv[r] = *(const float4*)&Xr[r][k0];
        #pragma unroll
        for (int u = 0; u < 4; ++u) wv[u] = *(const float4*)&Ws[(k0 + u) * 64 + c * 4];
        #pragma unroll
        for (int r = 0; r < 4; ++r) {
            float xa[4] = {xv[r].x, xv[r].y, xv[r].z, xv[r].w};
            #pragma unroll
            for (int u = 0; u < 4; ++u) {
                acc[r][0] += xa[u] * wv[u].x;
                acc[r][1] += xa[u] * wv[u].y;
                acc[r][2] += xa[u] * wv[u].z;
                acc[r][3] += xa[u] * wv[u].w;
            }
        }
    }

    const float as0 = asrc[col], as1 = asrc[col+1], as2 = asrc[col+2], as3 = asrc[col+3];
    const float ad0 = adst[col], ad1 = adst[col+1], ad2 = adst[col+2], ad3 = adst[col+3];
    const size_t cstride = (size_t)M * 16;
    float* __restrict__ Hq = Hc + (size_t)(col >> 4) * cstride + (col & 15);
    #pragma unroll
    for (int r = 0; r < 4; ++r) {
        int row = r0 + rg * 4 + r;
        float ps = acc[r][0]*as0 + acc[r][1]*as1 + acc[r][2]*as2 + acc[r][3]*as3;
        float pd = acc[r][0]*ad0 + acc[r][1]*ad1 + acc[r][2]*ad2 + acc[r][3]*ad3;
        #pragma unroll
        for (int mask = 1; mask < 16; mask <<= 1) {   // reduce over 16 col-groups
            ps += __shfl_xor(ps, mask);
            pd += __shfl_xor(pd, mask);
        }
        if (row < M) {
            *(float4*)&Hq[(size_t)row * 16] =
                make_float4(acc[r][0], acc[r][1], acc[r][2], acc[r][3]);
            if (c == 0) {
                atomicAdd(&als[row], ps);
                atomicAdd(&ald[row], pd);
            }
        }
    }
}

// ---------------- edge weights: packed u32 = (src<<16) | bf16(exp(leaky(e))) ----
// src < 65536 (N_NODES=50000) so 16 bits suffice. Denominator sums the ROUNDED
// bf16 weights so numerator/denominator are exactly consistent.
// Real degree comes from cnt[] (off[] is the padded layout); pad slots stay 0
// (src=0, w=+0.0) from the ew memset and contribute exactly nothing.
// csr is a pure stream (read once) -> nontemporal.
__global__ __launch_bounds__(256) void k_edgew(
        const float* __restrict__ als, const float* __restrict__ ald,
        const int* __restrict__ off, const int* __restrict__ cnt,
        const int* __restrict__ csr,
        unsigned* __restrict__ ew, float* __restrict__ invden, int n) {
    const int fl = threadIdx.x & 15;
    const int v = blockIdx.x * 16 + (threadIdx.x >> 4);
    if (v >= n) return;
    const int start = off[v], end = start + cnt[v];
    const float aldv = ald[v];
    float s = 0.f;
    for (int j = start + fl; j < end; j += 16) {
        int src = __builtin_nontemporal_load(&csr[j]);
        float e = als[src] + aldv;
        e = e > 0.f ? e : 0.2f * e;
        float w = __expf(e);
        unsigned u = __float_as_uint(w);
        unsigned r = (u + 0x7fffu + ((u >> 16) & 1u)) >> 16;   // RNE to bf16
        ew[j] = ((unsigned)src << 16) | r;
        s += __uint_as_float(r << 16);
    }
    #pragma unroll
    for (int d = 1; d < 16; d <<= 1) s += __shfl_xor(s, d);
    if (fl == 0) invden[v] = 1.f / (s + 1e-16f);
}

// ---------------- chunked SpMM: out[v] = invden * sum_e w_e * Hc[src_e] ------------
// Wave = 16 nodes; each 4-lane sub owns ONE node, lane = one FEATURE QUAD.
// One gather instruction fetches 16 independent 64B lines (1KB useful).
// L2 policy (r10 post-mortem): H-slice (3.2MB, heavily reused intra-XCD) must
// stay L2-resident; ew and out have ZERO intra-XCD reuse -> nontemporal, so
// they don't evict H (r10: evictions pushed FETCH 45->68MB and gathers to L3).
// Software pipeline: process 2 quads (8 edges) while prefetching the next 2 ew
// quads one iteration ahead -> 8 gathers + 2 ew loads in flight; the ew->gather
// dependency hides under the previous iteration's gathers. Conditional prefetch
// is per-lane exec-masked (no cross-lane ops anywhere -> divergence-safe).
template<int F, bool RELU>
__global__ __launch_bounds__(256) void k_spmm(
        const float* __restrict__ Hc, const unsigned* __restrict__ ew,
        const float* __restrict__ invden, const float* __restrict__ bias,
        const int* __restrict__ off, float* __restrict__ out, int n) {
    constexpr int NCH = F / 16;
    const int chunk = blockIdx.x % NCH;
    const int v = (blockIdx.x / NCH) * 64 + (threadIdx.x >> 2);
    if (v >= n) return;
    const int q = threadIdx.x & 3;                // feature quad 0..3
    const int start = off[v], end = off[v + 1];   // padded: (end-start) % 4 == 0, >= 4
    const float* __restrict__ Hch = Hc + (size_t)chunk * (size_t)n * 16 + q * 4;

    float4 a0 = make_float4(0.f, 0.f, 0.f, 0.f);
    float4 a1 = make_float4(0.f, 0.f, 0.f, 0.f);
    float4 a2 = make_float4(0.f, 0.f, 0.f, 0.f);
    float4 a3 = make_float4(0.f, 0.f, 0.f, 0.f);

    #define GAT(E, A)                                                  \
        {                                                              \
            float w_ = __uint_as_float((E) << 16);                     \
            float4 h_ = *(const float4*)&Hch[(size_t)((E) >> 16) * 16];\
            A.x += w_ * h_.x; A.y += w_ * h_.y;                        \
            A.z += w_ * h_.z; A.w += w_ * h_.w;                        \
        }
    #define GAT4(Q) GAT((Q).x, a0) GAT((Q).y, a1) GAT((Q).z, a2) GAT((Q).w, a3)

    int j = start;
    int rem = end - start;
    uint4v cAv = __builtin_nontemporal_load((const uint4v*)&ew[j]);
    uint4v cBv = cAv;
    if (rem >= 8) cBv = __builtin_nontemporal_load((const uint4v*)&ew[j + 4]);

    while (rem >= 8) {
        int nrem = rem - 8;
        uint4v nAv = cAv, nBv = cBv;               // placeholders (unused if no next)
        if (nrem >= 4) nAv = __builtin_nontemporal_load((const uint4v*)&ew[j + 8]);
        if (nrem >= 8) nBv = __builtin_nontemporal_load((const uint4v*)&ew[j + 12]);
        uint4 cA = make_uint4(cAv[0], cAv[1], cAv[2], cAv[3]);
        uint4 cB = make_uint4(cBv[0], cBv[1], cBv[2], cBv[3]);
        GAT4(cA)
        GAT4(cB)
        cAv = nAv; cBv = nBv;
        j += 8; rem = nrem;
    }
    if (rem >= 4) {                                // final single quad (rem == 4)
        uint4 cA = make_uint4(cAv[0], cAv[1], cAv[2], cAv[3]);
        GAT4(cA)
    }
    #undef GAT4
    #undef GAT

    const float inv = invden[v];
    const float4 b = *(const float4*)&bias[chunk * 16 + q * 4];
    float4v o;
    o[0] = (a0.x + a1.x + a2.x + a3.x) * inv + b.x;
    o[1] = (a0.y + a1.y + a2.y + a3.y) * inv + b.y;
    o[2] = (a0.z + a1.z + a2.z + a3.z) * inv + b.z;
    o[3] = (a0.w + a1.w + a2.w + a3.w) * inv + b.w;
    if (RELU) {
        o[0] = fmaxf(o[0], 0.f); o[1] = fmaxf(o[1], 0.f);
        o[2] = fmaxf(o[2], 0.f); o[3] = fmaxf(o[3], 0.f);
    }
    __builtin_nontemporal_store(o, (float4v*)&out[(size_t)v * F + chunk * 16 + q * 4]);
}

// ---------------- launch ----------------

extern "C" void kernel_launch(void* const* d_in, const int* in_sizes, int n_in,
                              void* d_out, int out_size, void* d_ws, size_t ws_size,
                              hipStream_t stream) {
    const float* x     = (const float*)d_in[0];
    const int*   ei    = (const int*)d_in[1];
    const float* W1    = (const float*)d_in[2];
    const float* as1   = (const float*)d_in[3];
    const float* ad1   = (const float*)d_in[4];
    const float* b1    = (const float*)d_in[5];
    const float* W2    = (const float*)d_in[6];
    const float* as2   = (const float*)d_in[7];
    const float* ad2   = (const float*)d_in[8];
    const float* b2    = (const float*)d_in[9];
    float* out = (float*)d_out;

    const int Nn = N_NODES, E = N_EDGES, ET = N_TOT_EDGES;

    // workspace carve-up (256B aligned)
    char* ws = (char*)d_ws;
    size_t o = 0;
    auto carve = [&](size_t bytes) { char* p = ws + o; o = (o + bytes + 255) & ~(size_t)255; return p; };
    int*      off  = (int*)carve((Nn + 1) * sizeof(int));
    int*      cnt  = (int*)carve(Nn * sizeof(int));
    int*      cur  = (int*)carve(Nn * sizeof(int));
    int*      bsum = (int*)carve(256 * sizeof(int));
    int*      csr  = (int*)carve((size_t)ET_PAD * sizeof(int));
    unsigned* ew   = (unsigned*)carve((size_t)ET_PAD * sizeof(unsigned));
    float*    h1   = (float*)carve((size_t)Nn * HID * sizeof(float));  // chunk-major; reused as h2
    float*    alsA = (float*)carve(Nn * sizeof(float));
    float*    aldA = (float*)carve(Nn * sizeof(float));
    float*    alsB = (float*)carve(Nn * sizeof(float));
    float*    aldB = (float*)carve(Nn * sizeof(float));
    float*    invd = (float*)carve(Nn * sizeof(float));
    float*    y1   = (float*)carve((size_t)Nn * HID * sizeof(float));
    float*    h2   = h1;

    const int nbN  = (Nn + 255) / 256;
    const int nbE  = (E + 255) / 256;
    const int nbET = (ET + 255) / 256;

    // CSR build (padded-to-4 segments)
    k_init<<<nbN, 256, 0, stream>>>(cnt, cur, alsA, aldA, alsB, aldB, Nn);
    k_count<<<nbE, 256, 0, stream>>>(ei + E, cnt, E);
    k_scan1<<<nbN, 256, 0, stream>>>(cnt, off, bsum, Nn);
    k_scan2<<<1, 256, 0, stream>>>(bsum, nbN);
    k_scan3<<<nbN, 256, 0, stream>>>(off, bsum, Nn);
    k_fill<<<nbET, 256, 0, stream>>>(ei, off, cur, csr, E, Nn);
    hipMemsetAsync(ew, 0, (size_t)ET_PAD * sizeof(unsigned), stream);  // pad slots -> (src=0, w=0)

    const int nbEW  = (Nn + 15) / 16;
    const int nbN64 = (Nn + 63) / 64;

    // layer 1
    gemm_att<HID><<<nbN64 * (HID / 64), 256, 0, stream>>>(x, W1, as1, ad1, h1, alsA, aldA, Nn);
    k_edgew<<<nbEW, 256, 0, stream>>>(alsA, aldA, off, cnt, csr, ew, invd, Nn);
    k_spmm<HID, true><<<nbN64 * (HID / 16), 256, 0, stream>>>(
        h1, ew, invd, b1, off, y1, Nn);

    // layer 2
    gemm_att<OUT_CH><<<nbN64 * (OUT_CH / 64), 256, 0, stream>>>(y1, W2, as2, ad2, h2, alsB, aldB, Nn);
    k_edgew<<<nbEW, 256, 0, stream>>>(alsB, aldB, off, cnt, csr, ew, invd, Nn);
    k_spmm<OUT_CH, false><<<nbN64 * (OUT_CH / 16), 256, 0, stream>>>(
        h2, ew, invd, b2, off, out, Nn);
}

// Round 12
// 233.008 us; speedup vs baseline: 1.2337x; 1.2337x over previous
//
#include <hip/hip_runtime.h>
#include <hip/hip_bf16.h>

#define N_NODES 50000
#define IN_CH 128
#define HID 128
#define OUT_CH 64
#define N_EDGES 800000
#define N_TOT_EDGES (N_EDGES + N_NODES)         // + self loops
#define ET_PAD (N_TOT_EDGES + 3 * N_NODES)      // worst-case pad-to-4 per node

typedef float float4v __attribute__((ext_vector_type(4)));

__device__ __forceinline__ unsigned bf16_rne(float f) {
    unsigned u = __float_as_uint(f);
    return (u + 0x7fffu + ((u >> 16) & 1u)) >> 16;
}

// ---------------- CSR build ----------------

__global__ void k_init(int* cnt, int* cur, float* alsA, float* aldA,
                       float* alsB, float* aldB, int n) {
    int i = blockIdx.x * 256 + threadIdx.x;
    if (i < n) {
        cnt[i] = 1; cur[i] = 0;              // self-loop contributes 1
        alsA[i] = 0.f; aldA[i] = 0.f;        // per-layer attention-dot accumulators
        alsB[i] = 0.f; aldB[i] = 0.f;        // (gemm atomically accumulates tile partials)
    }
}

__global__ void k_count(const int* __restrict__ dst_row, int* __restrict__ cnt, int e) {
    int i = blockIdx.x * 256 + threadIdx.x;
    if (i < e) atomicAdd(&cnt[dst_row[i]], 1);
}

// inclusive scan of PADDED counts -> off[i+1]; per-block sums to bsum.
__global__ void k_scan1(const int* __restrict__ cnt, int* __restrict__ off,
                        int* __restrict__ bsum, int n) {
    __shared__ int s[256];
    int t = threadIdx.x;
    int i = blockIdx.x * 256 + t;
    int v = (i < n) ? ((cnt[i] + 3) & ~3) : 0;
    s[t] = v;
    __syncthreads();
    for (int d = 1; d < 256; d <<= 1) {
        int x = (t >= d) ? s[t - d] : 0;
        __syncthreads();
        s[t] += x;
        __syncthreads();
    }
    if (i < n) off[i + 1] = s[t];
    if (t == 255) bsum[blockIdx.x] = s[255];
}

__global__ void k_scan2(int* __restrict__ bsum, int nb) {  // single block, nb <= 256
    __shared__ int s[256];
    int t = threadIdx.x;
    int v = (t < nb) ? bsum[t] : 0;
    s[t] = v;
    __syncthreads();
    for (int d = 1; d < 256; d <<= 1) {
        int x = (t >= d) ? s[t - d] : 0;
        __syncthreads();
        s[t] += x;
        __syncthreads();
    }
    if (t < nb) bsum[t] = s[t] - v;  // exclusive prefix
}

__global__ void k_scan3(int* __restrict__ off, const int* __restrict__ bsum, int n) {
    int i = blockIdx.x * 256 + threadIdx.x;
    if (i < n) off[i + 1] += bsum[blockIdx.x];
    if (i == 0) off[0] = 0;
}

__global__ void k_fill(const int* __restrict__ ei, const int* __restrict__ off,
                       int* __restrict__ cur, int* __restrict__ csr, int e, int n) {
    int i = blockIdx.x * 256 + threadIdx.x;
    if (i >= e + n) return;
    int src, dst;
    if (i < e) { src = ei[i]; dst = ei[e + i]; }
    else       { src = dst = i - e; }
    int pos = off[dst] + atomicAdd(&cur[dst], 1);
    csr[pos] = src;
}

// ---------------- GEMM (h = X @ W) + fused attention dots ----------------
// Only W staged in LDS (32KB -> 4-5 blocks/CU). X streams via broadcast float4.
// 64x64 tile, thread = 4x4. Attention dots: shfl_xor over 16 col-lanes +
// one atomicAdd per (row, col-tile) into zeroed per-layer buffers.
// BF16OUT=true  (layer 1): H chunk-major bf16, 32-feat chunks (3.2MB slice).
// BF16OUT=false (layer 2): H chunk-major f32, 16-feat chunks (3.2MB slice).
template<int N, bool BF16OUT>
__global__ __launch_bounds__(256) void gemm_att(
        const float* __restrict__ X, const float* __restrict__ W,
        const float* __restrict__ asrc, const float* __restrict__ adst,
        void* __restrict__ HcV, float* __restrict__ als, float* __restrict__ ald,
        int M) {
    constexpr int K = 128;
    constexpr int CT = N / 64;                 // col tiles (2 or 1)
    __shared__ float Ws[K * 64];               // 32 KB
    const int ct = blockIdx.x % CT;
    const int r0 = (blockIdx.x / CT) * 64;
    const int t  = threadIdx.x;
    const int c  = t & 15;                     // col group (4 cols each)
    const int rg = t >> 4;                     // row group (4 rows each)
    const int col = ct * 64 + c * 4;

    for (int i = t * 4; i < K * 64; i += 1024) {
        int k = i >> 6, cc = i & 63;
        *(float4*)&Ws[i] = *(const float4*)&W[(size_t)k * N + ct * 64 + cc];
    }
    __syncthreads();

    const float* Xr[4];
    #pragma unroll
    for (int r = 0; r < 4; ++r) {
        int row = r0 + rg * 4 + r; if (row >= M) row = M - 1;
        Xr[r] = X + (size_t)row * K;
    }

    float acc[4][4] = {};
    for (int k0 = 0; k0 < K; k0 += 4) {
        float4 xv[4], wv[4];
        #pragma unroll
        for (int r = 0; r < 4; ++r) xv[r] = *(const float4*)&Xr[r][k0];
        #pragma unroll
        for (int u = 0; u < 4; ++u) wv[u] = *(const float4*)&Ws[(k0 + u) * 64 + c * 4];
        #pragma unroll
        for (int r = 0; r < 4; ++r) {
            float xa[4] = {xv[r].x, xv[r].y, xv[r].z, xv[r].w};
            #pragma unroll
            for (int u = 0; u < 4; ++u) {
                acc[r][0] += xa[u] * wv[u].x;
                acc[r][1] += xa[u] * wv[u].y;
                acc[r][2] += xa[u] * wv[u].z;
                acc[r][3] += xa[u] * wv[u].w;
            }
        }
    }

    const float as0 = asrc[col], as1 = asrc[col+1], as2 = asrc[col+2], as3 = asrc[col+3];
    const float ad0 = adst[col], ad1 = adst[col+1], ad2 = adst[col+2], ad3 = adst[col+3];
    #pragma unroll
    for (int r = 0; r < 4; ++r) {
        int row = r0 + rg * 4 + r;
        float ps = acc[r][0]*as0 + acc[r][1]*as1 + acc[r][2]*as2 + acc[r][3]*as3;
        float pd = acc[r][0]*ad0 + acc[r][1]*ad1 + acc[r][2]*ad2 + acc[r][3]*ad3;
        #pragma unroll
        for (int mask = 1; mask < 16; mask <<= 1) {   // reduce over 16 col-groups
            ps += __shfl_xor(ps, mask);
            pd += __shfl_xor(pd, mask);
        }
        if (row < M) {
            if (BF16OUT) {
                // bf16 chunk-major: Hb[chunk][row][32], chunk = col>>5
                unsigned short* Hb = (unsigned short*)HcV;
                size_t cstride = (size_t)M * 32;
                unsigned short* Hq = Hb + (size_t)(col >> 5) * cstride
                                   + (size_t)row * 32 + (col & 31);
                uint2 p;
                p.x = bf16_rne(acc[r][0]) | (bf16_rne(acc[r][1]) << 16);
                p.y = bf16_rne(acc[r][2]) | (bf16_rne(acc[r][3]) << 16);
                *(uint2*)Hq = p;
            } else {
                // f32 chunk-major: Hc[chunk][row][16], chunk = col>>4
                float* Hc = (float*)HcV;
                size_t cstride = (size_t)M * 16;
                float* Hq = Hc + (size_t)(col >> 4) * cstride
                          + (size_t)row * 16 + (col & 15);
                *(float4*)Hq = make_float4(acc[r][0], acc[r][1], acc[r][2], acc[r][3]);
            }
            if (c == 0) {
                atomicAdd(&als[row], ps);
                atomicAdd(&ald[row], pd);
            }
        }
    }
}

// ---------------- edge weights: packed u32 = (src<<16) | bf16(exp(leaky(e))) ----
// Denominator sums the ROUNDED bf16 weights (numerator/denominator consistent).
// Pad slots stay 0 (src=0, w=+0.0) from the ew memset -> contribute nothing.
// No segment-max: glorot-scale scores (|e| < ~10) make exp() f32-safe.
__global__ __launch_bounds__(256) void k_edgew(
        const float* __restrict__ als, const float* __restrict__ ald,
        const int* __restrict__ off, const int* __restrict__ cnt,
        const int* __restrict__ csr,
        unsigned* __restrict__ ew, float* __restrict__ invden, int n) {
    const int fl = threadIdx.x & 15;
    const int v = blockIdx.x * 16 + (threadIdx.x >> 4);
    if (v >= n) return;
    const int start = off[v], end = start + cnt[v];
    const float aldv = ald[v];
    float s = 0.f;
    for (int j = start + fl; j < end; j += 16) {
        int src = __builtin_nontemporal_load(&csr[j]);
        float e = als[src] + aldv;
        e = e > 0.f ? e : 0.2f * e;
        unsigned r = bf16_rne(__expf(e));
        ew[j] = ((unsigned)src << 16) | r;
        s += __uint_as_float(r << 16);
    }
    #pragma unroll
    for (int d = 1; d < 16; d <<= 1) s += __shfl_xor(s, d);
    if (fl == 0) invden[v] = 1.f / (s + 1e-16f);
}

// ---------------- layer-1 SpMM (bf16 H, 32-feature chunks, 4 passes) ------------
// Wave = 16 nodes; 4-lane sub owns one node; lane = 8 bf16 feats (16B).
// One gather instr = 16 independent 64B lines (full node-chunk each) -> same
// MLP as r10 but HALF the passes (4 vs 8): half the gathers, half the ew reads.
// Cached ew loads (L1 spatial reuse; r11 showed nt loads on this path regress).
// Simple r10-style loop: 2 quads/iter, 8 gathers in flight, no cross-lane ops.
__global__ __launch_bounds__(256) void k_spmm_bf16(
        const unsigned short* __restrict__ Hb, const unsigned* __restrict__ ew,
        const float* __restrict__ invden, const float* __restrict__ bias,
        const int* __restrict__ off, float* __restrict__ out, int n) {
    const int chunk = blockIdx.x & 3;             // NCH = 128/32 = 4
    const int v = (blockIdx.x >> 2) * 64 + (threadIdx.x >> 2);
    if (v >= n) return;
    const int q = threadIdx.x & 3;                // 8-feat group 0..3
    const int start = off[v], end = off[v + 1];   // padded: multiple of 4, >= 4
    const unsigned short* __restrict__ Hch = Hb + (size_t)chunk * (size_t)n * 32 + q * 8;

    float a0[8] = {}, a1[8] = {}, a2[8] = {}, a3[8] = {};

    #define GATB(E, A)                                                   \
        {                                                                \
            float w_ = __uint_as_float((E) << 16);                       \
            uint4 h_ = *(const uint4*)&Hch[(size_t)((E) >> 16) * 32];    \
            A[0] += w_ * __uint_as_float(h_.x << 16);                    \
            A[1] += w_ * __uint_as_float(h_.x & 0xffff0000u);            \
            A[2] += w_ * __uint_as_float(h_.y << 16);                    \
            A[3] += w_ * __uint_as_float(h_.y & 0xffff0000u);            \
            A[4] += w_ * __uint_as_float(h_.z << 16);                    \
            A[5] += w_ * __uint_as_float(h_.z & 0xffff0000u);            \
            A[6] += w_ * __uint_as_float(h_.w << 16);                    \
            A[7] += w_ * __uint_as_float(h_.w & 0xffff0000u);            \
        }
    #define GATB4(Q) GATB((Q).x, a0) GATB((Q).y, a1) GATB((Q).z, a2) GATB((Q).w, a3)

    int j = start;
    for (; j + 4 < end; j += 8) {
        uint4 eA = *(const uint4*)&ew[j];
        uint4 eB = *(const uint4*)&ew[j + 4];
        GATB4(eA)
        GATB4(eB)
    }
    if (j < end) {
        uint4 eA = *(const uint4*)&ew[j];
        GATB4(eA)
    }
    #undef GATB4
    #undef GATB

    const float inv = invden[v];
    float* __restrict__ op = out + (size_t)v * HID + chunk * 32 + q * 8;
    const float* __restrict__ bp = bias + chunk * 32 + q * 8;
    float4 o0, o1;
    o0.x = fmaxf((a0[0]+a1[0]+a2[0]+a3[0]) * inv + bp[0], 0.f);
    o0.y = fmaxf((a0[1]+a1[1]+a2[1]+a3[1]) * inv + bp[1], 0.f);
    o0.z = fmaxf((a0[2]+a1[2]+a2[2]+a3[2]) * inv + bp[2], 0.f);
    o0.w = fmaxf((a0[3]+a1[3]+a2[3]+a3[3]) * inv + bp[3], 0.f);
    o1.x = fmaxf((a0[4]+a1[4]+a2[4]+a3[4]) * inv + bp[4], 0.f);
    o1.y = fmaxf((a0[5]+a1[5]+a2[5]+a3[5]) * inv + bp[5], 0.f);
    o1.z = fmaxf((a0[6]+a1[6]+a2[6]+a3[6]) * inv + bp[6], 0.f);
    o1.w = fmaxf((a0[7]+a1[7]+a2[7]+a3[7]) * inv + bp[7], 0.f);
    *(float4*)&op[0] = o0;
    *(float4*)&op[4] = o1;
}

// ---------------- layer-2 SpMM (f32 H, 16-feature chunks) -- r10 structure ------
__global__ __launch_bounds__(256) void k_spmm_f32(
        const float* __restrict__ Hc, const unsigned* __restrict__ ew,
        const float* __restrict__ invden, const float* __restrict__ bias,
        const int* __restrict__ off, float* __restrict__ out, int n) {
    const int chunk = blockIdx.x & 3;             // NCH = 64/16 = 4
    const int v = (blockIdx.x >> 2) * 64 + (threadIdx.x >> 2);
    if (v >= n) return;
    const int q = threadIdx.x & 3;                // feature quad 0..3
    const int start = off[v], end = off[v + 1];
    const float* __restrict__ Hch = Hc + (size_t)chunk * (size_t)n * 16 + q * 4;

    float4 a0 = make_float4(0.f, 0.f, 0.f, 0.f);
    float4 a1 = make_float4(0.f, 0.f, 0.f, 0.f);
    float4 a2 = make_float4(0.f, 0.f, 0.f, 0.f);
    float4 a3 = make_float4(0.f, 0.f, 0.f, 0.f);

    #define GAT(E, A)                                                  \
        {                                                              \
            float w_ = __uint_as_float((E) << 16);                     \
            float4 h_ = *(const float4*)&Hch[(size_t)((E) >> 16) * 16];\
            A.x += w_ * h_.x; A.y += w_ * h_.y;                        \
            A.z += w_ * h_.z; A.w += w_ * h_.w;                        \
        }
    #define GAT4(Q) GAT((Q).x, a0) GAT((Q).y, a1) GAT((Q).z, a2) GAT((Q).w, a3)

    int j = start;
    for (; j + 4 < end; j += 8) {
        uint4 eA = *(const uint4*)&ew[j];
        uint4 eB = *(const uint4*)&ew[j + 4];
        GAT4(eA)
        GAT4(eB)
    }
    if (j < end) {
        uint4 eA = *(const uint4*)&ew[j];
        GAT4(eA)
    }
    #undef GAT4
    #undef GAT

    const float inv = invden[v];
    const float4 b = *(const float4*)&bias[chunk * 16 + q * 4];
    float4v o;
    o[0] = (a0.x + a1.x + a2.x + a3.x) * inv + b.x;
    o[1] = (a0.y + a1.y + a2.y + a3.y) * inv + b.y;
    o[2] = (a0.z + a1.z + a2.z + a3.z) * inv + b.z;
    o[3] = (a0.w + a1.w + a2.w + a3.w) * inv + b.w;
    // final output: pure write-stream -> nontemporal (don't evict H from L2)
    __builtin_nontemporal_store(o, (float4v*)&out[(size_t)v * OUT_CH + chunk * 16 + q * 4]);
}

// ---------------- launch ----------------

extern "C" void kernel_launch(void* const* d_in, const int* in_sizes, int n_in,
                              void* d_out, int out_size, void* d_ws, size_t ws_size,
                              hipStream_t stream) {
    const float* x     = (const float*)d_in[0];
    const int*   ei    = (const int*)d_in[1];
    const float* W1    = (const float*)d_in[2];
    const float* as1   = (const float*)d_in[3];
    const float* ad1   = (const float*)d_in[4];
    const float* b1    = (const float*)d_in[5];
    const float* W2    = (const float*)d_in[6];
    const float* as2   = (const float*)d_in[7];
    const float* ad2   = (const float*)d_in[8];
    const float* b2    = (const float*)d_in[9];
    float* out = (float*)d_out;

    const int Nn = N_NODES, E = N_EDGES, ET = N_TOT_EDGES;

    // workspace carve-up (256B aligned)
    char* ws = (char*)d_ws;
    size_t o = 0;
    auto carve = [&](size_t bytes) { char* p = ws + o; o = (o + bytes + 255) & ~(size_t)255; return p; };
    int*            off  = (int*)carve((Nn + 1) * sizeof(int));
    int*            cnt  = (int*)carve(Nn * sizeof(int));
    int*            cur  = (int*)carve(Nn * sizeof(int));
    int*            bsum = (int*)carve(256 * sizeof(int));
    int*            csr  = (int*)carve((size_t)ET_PAD * sizeof(int));
    unsigned*       ew   = (unsigned*)carve((size_t)ET_PAD * sizeof(unsigned));
    unsigned short* h1b  = (unsigned short*)carve((size_t)Nn * HID * sizeof(unsigned short));
    float*          h2   = (float*)carve((size_t)Nn * OUT_CH * sizeof(float));
    float*          alsA = (float*)carve(Nn * sizeof(float));
    float*          aldA = (float*)carve(Nn * sizeof(float));
    float*          alsB = (float*)carve(Nn * sizeof(float));
    float*          aldB = (float*)carve(Nn * sizeof(float));
    float*          invd = (float*)carve(Nn * sizeof(float));
    float*          y1   = (float*)carve((size_t)Nn * HID * sizeof(float));

    const int nbN  = (Nn + 255) / 256;
    const int nbE  = (E + 255) / 256;
    const int nbET = (ET + 255) / 256;

    // CSR build (padded-to-4 segments)
    k_init<<<nbN, 256, 0, stream>>>(cnt, cur, alsA, aldA, alsB, aldB, Nn);
    k_count<<<nbE, 256, 0, stream>>>(ei + E, cnt, E);
    k_scan1<<<nbN, 256, 0, stream>>>(cnt, off, bsum, Nn);
    k_scan2<<<1, 256, 0, stream>>>(bsum, nbN);
    k_scan3<<<nbN, 256, 0, stream>>>(off, bsum, Nn);
    k_fill<<<nbET, 256, 0, stream>>>(ei, off, cur, csr, E, Nn);
    hipMemsetAsync(ew, 0, (size_t)ET_PAD * sizeof(unsigned), stream);  // pads -> (src=0, w=0)

    const int nbEW  = (Nn + 15) / 16;
    const int nbN64 = (Nn + 63) / 64;

    // layer 1: H in bf16 (32-feat chunks, 4 spmm passes)
    gemm_att<HID, true><<<nbN64 * (HID / 64), 256, 0, stream>>>(
        x, W1, as1, ad1, h1b, alsA, aldA, Nn);
    k_edgew<<<nbEW, 256, 0, stream>>>(alsA, aldA, off, cnt, csr, ew, invd, Nn);
    k_spmm_bf16<<<nbN64 * 4, 256, 0, stream>>>(h1b, ew, invd, b1, off, y1, Nn);

    // layer 2: H in f32 (16-feat chunks, 4 spmm passes)
    gemm_att<OUT_CH, false><<<nbN64 * (OUT_CH / 64), 256, 0, stream>>>(
        y1, W2, as2, ad2, h2, alsB, aldB, Nn);
    k_edgew<<<nbEW, 256, 0, stream>>>(alsB, aldB, off, cnt, csr, ew, invd, Nn);
    k_spmm_f32<<<nbN64 * 4, 256, 0, stream>>>(h2, ew, invd, b2, off, out, Nn);
}